// Round 2
// baseline (86.783 us; speedup 1.0000x reference)
//
#include <hip/hip_runtime.h>

// CSPN-style spatially-varying 7x7 filter.
// out[b,y,x] = sum_{i,j} gw[b, 7i+j, y+3, x+3] * src[b, y+3-i, x+3-j]
// src = hn except tap t==24 (i=j=3) which uses h0[b,y,x].
// Out-of-range hn reads are zero.
//
// R2: 4 pixels per thread. gw read as (word-aligned, 16B-misaligned) float4 —
// 1 KB contiguous per wave per tap. hn read as a 12-float register window per
// tap-row (3 aligned float4 loads, branch-free edge zeroing). Aligned float4
// out store.

constexpr int B = 8, H = 512, W = 512, K = 7, HP = H + K - 1; // 518
constexpr long PLANE = (long)HP * HP;                          // 268324

__global__ __launch_bounds__(256) void cspn_kernel(
    const float* __restrict__ gw, const float* __restrict__ hn,
    const float* __restrict__ h0, float* __restrict__ out)
{
    int q = blockIdx.x * 256 + threadIdx.x;   // quad index
    int x0 = (q & 127) << 2;                  // 0..508, multiple of 4
    int y  = (q >> 7) & 511;
    int b  = q >> 16;

    // gw pointer for tap 0, pixel x0 (word offset is odd -> 4B-aligned only)
    const float* gp = gw + (size_t)b * 49 * PLANE + (size_t)(y + 3) * HP + (x0 + 3);
    const float* hb = hn + (size_t)b * H * W;

    // center-tap source: h0[y, x0..x0+3], aligned
    const float4 h0v = *reinterpret_cast<const float4*>(
        h0 + ((size_t)b * H + y) * W + x0);

    float acc0 = 0.f, acc1 = 0.f, acc2 = 0.f, acc3 = 0.f;
    const float4 z4 = make_float4(0.f, 0.f, 0.f, 0.f);

    #pragma unroll
    for (int i = 0; i < K; ++i) {
        int sy = y + 3 - i;
        bool oky = (unsigned)sy < (unsigned)H;          // wave-uniform
        const float* hrow = hb + (size_t)(oky ? sy : 0) * W;

        // window w[0..11] = hn[sy, x0-4 .. x0+7], zeros out of range
        float4 wA = (oky && x0 > 0)   ? *reinterpret_cast<const float4*>(hrow + x0 - 4) : z4;
        float4 wB = oky               ? *reinterpret_cast<const float4*>(hrow + x0)     : z4;
        float4 wC = (oky && x0 < 508) ? *reinterpret_cast<const float4*>(hrow + x0 + 4) : z4;
        float w[12] = { wA.x, wA.y, wA.z, wA.w,
                        wB.x, wB.y, wB.z, wB.w,
                        wC.x, wC.y, wC.z, wC.w };

        #pragma unroll
        for (int j = 0; j < K; ++j) {
            int t = i * K + j;
            // gw quad for pixels x0..x0+3 at this tap (16B-misaligned OK)
            float4 g = *reinterpret_cast<const float4*>(gp + (size_t)t * PLANE);
            if (t == 24) {
                acc0 += g.x * h0v.x;
                acc1 += g.y * h0v.y;
                acc2 += g.z * h0v.z;
                acc3 += g.w * h0v.w;
            } else {
                // pixel p, tap j reads window index p + 7 - j  (in [1,10])
                acc0 += g.x * w[7 - j];
                acc1 += g.y * w[8 - j];
                acc2 += g.z * w[9 - j];
                acc3 += g.w * w[10 - j];
            }
        }
    }

    float4 r = make_float4(acc0, acc1, acc2, acc3);
    *reinterpret_cast<float4*>(out + ((size_t)b * H + y) * W + x0) = r;
}

extern "C" void kernel_launch(void* const* d_in, const int* in_sizes, int n_in,
                              void* d_out, int out_size, void* d_ws, size_t ws_size,
                              hipStream_t stream)
{
    const float* gw = (const float*)d_in[0];
    const float* hn = (const float*)d_in[1];
    const float* h0 = (const float*)d_in[2];
    float* out = (float*)d_out;

    int quads = B * H * W / 4;             // 524288
    int blocks = quads / 256;              // 2048
    cspn_kernel<<<blocks, 256, 0, stream>>>(gw, hn, h0, out);
}